// Round 2
// baseline (184.695 us; speedup 1.0000x reference)
//
#include <hip/hip_runtime.h>
#include <hip/hip_bf16.h>
#include <math.h>

#define BDIM 8192
#define DDIM 2048
#define CDIM 1000
#define NPAD 1024
#define BK   64

// ws layout (bytes):
//   xb bf16 [8192*2048] = 33554432 @ 0
//   Bt bf16 [1024*2048] =  4194304 @ 33554432
//   P0 bf16 [8192*1000] = 16384000 @ 37748736   (split-K partial, k-half 0)
//   P1 bf16 [8192*1000] = 16384000 @ 54132736   (split-K partial, k-half 1)
// total = 70516736
#define WS_BT_OFFSET  33554432ULL
#define WS_P0_OFFSET  37748736ULL
#define WS_P1_OFFSET  54132736ULL
#define WS_NEED       70516736ULL

typedef __attribute__((ext_vector_type(8))) short short8;
typedef __attribute__((ext_vector_type(4))) float floatx4;

__device__ __forceinline__ unsigned short f2bf(float f) {
    union { float f; unsigned u; } a; a.f = f;
    unsigned u = a.u;
    u = (u + 0x7fff + ((u >> 16) & 1)) >> 16;   // RNE, finite inputs
    return (unsigned short)u;
}

__device__ __forceinline__ float bf2f(unsigned short h) {
    union { unsigned u; float f; } a; a.u = ((unsigned)h) << 16;
    return a.f;
}

__device__ __forceinline__ void async_copy16(const void* gp, void* lp) {
    __builtin_amdgcn_global_load_lds(
        (const __attribute__((address_space(1))) void*)gp,
        (__attribute__((address_space(3))) void*)lp,
        16, 0, 0);
}

// ---- kernel 1: fused x->bf16 (blocks 0..2047, grid-stride x8) and
//      W->Bt transpose (blocks 2048..4095) ----
__global__ __launch_bounds__(256) void cvt_kernel(
    const float* __restrict__ x, unsigned short* __restrict__ xb,
    const float* __restrict__ W, unsigned short* __restrict__ Bt)
{
    const int blk = blockIdx.x;
    const int t   = threadIdx.x;
    if (blk < 2048) {
        // 8192*2048/4 = 4194304 float4s = 2048 blk * 256 thr * 8 iters
        int i = blk * 256 + t;
        #pragma unroll
        for (int it = 0; it < 8; it++) {
            float4 v = ((const float4*)x)[i];
            ushort4 o;
            o.x = f2bf(v.x); o.y = f2bf(v.y); o.z = f2bf(v.z); o.w = f2bf(v.w);
            ((ushort4*)xb)[i] = o;
            i += 2048 * 256;
        }
    } else {
        __shared__ float tile[32][33];
        const int b2 = blk - 2048;           // 64 k-tiles x 32 n-tiles
        const int k0 = (b2 & 63) * 32;
        const int n0 = (b2 >> 6) * 32;
        const int tx = t & 31, ty = t >> 5;  // 32 x 8
        #pragma unroll
        for (int i = 0; i < 4; i++) {
            int k = k0 + ty + i * 8;
            int n = n0 + tx;
            tile[ty + i * 8][tx] = (n < CDIM) ? W[(size_t)k * CDIM + n] : 0.0f;
        }
        __syncthreads();
        #pragma unroll
        for (int i = 0; i < 4; i++) {
            int n = n0 + ty + i * 8;
            int k = k0 + tx;
            Bt[(size_t)n * DDIM + k] = f2bf(tile[tx][ty + i * 8]);
        }
    }
}

// ---- fallback GEMM body (R7 structure) for the small-ws path ----
template <bool BF16OUT>
__device__ __forceinline__ void gemm_body(
    const unsigned short* __restrict__ A,
    const unsigned short* __restrict__ Bt,
    void* __restrict__ Cv,
    int mBase, int nBase, int kBase, int kIters,
    unsigned short* As, unsigned short* Bs)
{
    const int t    = threadIdx.x;
    const int wave = t >> 6;
    const int lane = t & 63;
    const int wm   = wave & 1;
    const int wn   = wave >> 1;
    const int quad = lane >> 4;
    const int l16  = lane & 15;

    floatx4 acc[4][4] = {};

    const int rowA = t >> 3;
    const int csw  = ((t & 7) ^ (rowA & 7)) * 16;
    const char* Ag = (const char*)A  + ((size_t)(mBase + rowA) * DDIM + kBase) * 2 + csw;
    const char* Bg = (const char*)Bt + ((size_t)(nBase + rowA) * DDIM + kBase) * 2 + csw;
    char* AsDst = (char*)As + t * 16;
    char* BsDst = (char*)Bs + t * 16;

    const int xorb0 = ((0 * 4 + quad) ^ (l16 & 7)) * 8;
    const int xorb1 = ((1 * 4 + quad) ^ (l16 & 7)) * 8;

    for (int kt = 0; kt < kIters * BK; kt += BK) {
        const char* a = Ag + kt * 2;
        const char* b = Bg + kt * 2;
        #pragma unroll
        for (int r = 0; r < 4; r++) {
            async_copy16(a + (size_t)r * 32 * DDIM * 2, AsDst + r * 4096);
            async_copy16(b + (size_t)r * 32 * DDIM * 2, BsDst + r * 4096);
        }
        __syncthreads();

        #pragma unroll
        for (int ks = 0; ks < 2; ks++) {
            const int xorb = ks ? xorb1 : xorb0;
            short8 af[4], bfr[4];
            #pragma unroll
            for (int mi = 0; mi < 4; mi++)
                af[mi] = *(const short8*)(As + (wm * 64 + mi * 16 + l16) * BK + xorb);
            #pragma unroll
            for (int ni = 0; ni < 4; ni++)
                bfr[ni] = *(const short8*)(Bs + (wn * 64 + ni * 16 + l16) * BK + xorb);
            #pragma unroll
            for (int mi = 0; mi < 4; mi++)
                #pragma unroll
                for (int ni = 0; ni < 4; ni++)
                    acc[mi][ni] = __builtin_amdgcn_mfma_f32_16x16x32_bf16(
                        af[mi], bfr[ni], acc[mi][ni], 0, 0, 0);
        }
        __syncthreads();
    }

    #pragma unroll
    for (int mi = 0; mi < 4; mi++) {
        int row0 = mBase + wm * 64 + mi * 16 + quad * 4;
        #pragma unroll
        for (int ni = 0; ni < 4; ni++) {
            int col = nBase + wn * 64 + ni * 16 + l16;
            if (col < CDIM) {
                #pragma unroll
                for (int rg = 0; rg < 4; rg++) {
                    if (BF16OUT)
                        ((unsigned short*)Cv)[(size_t)(row0 + rg) * CDIM + col] =
                            f2bf(acc[mi][ni][rg]);
                    else
                        ((float*)Cv)[(size_t)(row0 + rg) * CDIM + col] = acc[mi][ni][rg];
                }
            }
        }
    }
}

// ---- single-K fallback: grid 512, fp32 out ----
__global__ __launch_bounds__(256, 2) void gemm_single_kernel(
    const unsigned short* __restrict__ A,
    const unsigned short* __restrict__ Bt,
    float* __restrict__ C0)
{
    __shared__ unsigned short As[128 * BK];
    __shared__ unsigned short Bs[128 * BK];

    const int L   = blockIdx.x;          // 0..511
    const int xcd = L & 7;
    const int s   = L >> 3;              // 0..63
    const int m_t = xcd * 8 + (s >> 3);
    const int n_t = s & 7;

    gemm_body<false>(A, Bt, C0, m_t * 128, n_t * 128, 0, DDIM / BK, As, Bs);
}

// =====================================================================
// 8-phase 256x256 split-K GEMM.  R1 fix: UNIFORM tile-(j+2) staging.
// All 4 staging units of tile j+2 are issued during iter j, each into
// the quarter of buf(j) whose fragment reads completed one barrier
// earlier:  P1: A-u0 + B-u0 ; P2: B-u1 ; P3: A-u1.  The counted wait
// vmcnt(8) at P3(j) leaves exactly tile j+2's 8 loads outstanding and
// confirms tile j+1, whose loads were issued a full iteration earlier
// (4-6 phases of latency cover vs 3 in R0).
// Staging units (rows within 256-row tile):
//   A-u0 = {q, q+128}            read at P0  -> staged at P1
//   A-u1 = {q+64, q+192}         read at P2  -> staged at P3
//   B-u0 = {q+(q&32), +128}      read at P0  -> staged at P1
//   B-u1 = B-u0 + 32             read at P1  -> staged at P2
// =====================================================================

#define STAGE_A(BUF, EXT, KO)                                                 \
    do {                                                                      \
        _Pragma("unroll")                                                     \
        for (int h = 0; h < 2; h++) {                                         \
            const int row_ = rA0 + (EXT) + h * 128;                           \
            async_copy16(gA + (size_t)row_ * DDIM + (KO),                     \
                         &As[BUF][row_ * BK + c8]);                           \
        }                                                                     \
    } while (0)

#define STAGE_B(BUF, EXT, KO)                                                 \
    do {                                                                      \
        _Pragma("unroll")                                                     \
        for (int h = 0; h < 2; h++) {                                         \
            const int row_ = rB0 + (EXT) + h * 128;                           \
            async_copy16(gB + (size_t)row_ * DDIM + (KO),                     \
                         &Bs[BUF][row_ * BK + c8]);                           \
        }                                                                     \
    } while (0)

#define LOADA(BUF, MQ)                                                        \
    do {                                                                      \
        _Pragma("unroll")                                                     \
        for (int mf = 0; mf < 4; mf++) {                                      \
            const int r_ = (arA + (MQ) * 64 + mf * 16) * BK;                  \
            af[mf][0] = *(const short8*)&As[BUF][r_ + xorb0];                 \
            af[mf][1] = *(const short8*)&As[BUF][r_ + xorb1];                 \
        }                                                                     \
    } while (0)

#define LOADB(BUF, NQ, BF)                                                    \
    do {                                                                      \
        _Pragma("unroll")                                                     \
        for (int nf = 0; nf < 2; nf++) {                                      \
            const int r_ = (arB + (NQ) * 32 + nf * 16) * BK;                  \
            BF[nf][0] = *(const short8*)&Bs[BUF][r_ + xorb0];                 \
            BF[nf][1] = *(const short8*)&Bs[BUF][r_ + xorb1];                 \
        }                                                                     \
    } while (0)

#define MMAC(MQ, NQ, BF)                                                      \
    do {                                                                      \
        __builtin_amdgcn_s_setprio(1);                                        \
        _Pragma("unroll")                                                     \
        for (int mf = 0; mf < 4; mf++) {                                      \
            _Pragma("unroll")                                                 \
            for (int nf = 0; nf < 2; nf++) {                                  \
                floatx4 c_ = acc[(MQ) * 4 + mf][(NQ) * 2 + nf];               \
                c_ = __builtin_amdgcn_mfma_f32_16x16x32_bf16(                 \
                    af[mf][0], BF[nf][0], c_, 0, 0, 0);                       \
                c_ = __builtin_amdgcn_mfma_f32_16x16x32_bf16(                 \
                    af[mf][1], BF[nf][1], c_, 0, 0, 0);                       \
                acc[(MQ) * 4 + mf][(NQ) * 2 + nf] = c_;                       \
            }                                                                 \
        }                                                                     \
        __builtin_amdgcn_s_setprio(0);                                        \
    } while (0)

#define RAW_BARRIER() asm volatile("s_barrier" ::: "memory")

__global__ __launch_bounds__(512) void gemm8_kernel(
    const unsigned short* __restrict__ A,
    const unsigned short* __restrict__ Bt,
    unsigned short* __restrict__ P0, unsigned short* __restrict__ P1)
{
    __shared__ unsigned short As[2][256 * BK];
    __shared__ unsigned short Bs[2][256 * BK];

    const int t    = threadIdx.x;
    const int wave = t >> 6;
    const int lane = t & 63;
    const int wm   = wave >> 2;          // 0..1  (M half)
    const int wn   = wave & 3;           // 0..3  (N quarter)
    const int quad = lane >> 4;
    const int l16  = lane & 15;

    // XCD-swizzled block mapping: 256 blocks -> 8 XCDs x 32.
    const int L    = blockIdx.x;
    const int g    = (L & 7) * 32 + (L >> 3);   // bijective, nwg%8==0
    const int z    = g & 1;                     // K-split
    const int tid2 = g >> 1;                    // 0..127
    const int mBase = (tid2 >> 2) * 256;
    const int nBase = (tid2 & 3) * 256;
    const int kBase = z * (DDIM / 2);
    const int NTt   = (DDIM / 2) / BK;          // 16 K-tiles

    // --- staging precompute
    const int c8  = (t & 7) << 3;               // dst chunk col (ushorts)
    const int q0  = t >> 3;                     // 0..63
    const int csw = (((t & 7) ^ (q0 & 7)) << 3);// pre-swizzled src chunk
    const int rA0 = q0;                         // A-u0 rows: q0, q0+128
    const int rB0 = q0 + (q0 & 32);             // B-u0 rows: rb, rb+128
    const unsigned short* gA = A  + (size_t)mBase * DDIM + kBase + csw;
    const unsigned short* gB = Bt + (size_t)nBase * DDIM + kBase + csw;

    // --- fragment-read precompute
    const int xorb0 = ((0 * 4 + quad) ^ (l16 & 7)) << 3;
    const int xorb1 = ((1 * 4 + quad) ^ (l16 & 7)) << 3;
    const int arA = wm * 128 + l16;
    const int arB = wn * 64 + l16;

    floatx4 acc[8][4] = {};
    short8 af[4][2], bf0[2][2], bf1[2][2];

    // --- prologue: stage tile0 + tile1 fully (16 loads), confirm tile0
    STAGE_A(0, 0, 0);
    STAGE_A(0, 64, 0);
    STAGE_B(0, 0, 0);
    STAGE_B(0, 32, 0);
    STAGE_A(1, 0, BK);
    STAGE_A(1, 64, BK);
    STAGE_B(1, 0, BK);
    STAGE_B(1, 32, BK);
    asm volatile("s_waitcnt vmcnt(8)" ::: "memory");  // tile0 confirmed
    RAW_BARRIER();

    for (int j = 0; j < NTt; j++) {
        const int buf = j & 1;
        const int ko2 = (j + 2) * BK;
        const bool s2 = (j + 2 < NTt);

        // P0: read af(m0) + bf0  (12 ds_reads, no staging)
        if (buf == 0) { LOADA(0, 0); LOADB(0, 0, bf0); }
        else          { LOADA(1, 0); LOADB(1, 0, bf0); }
        RAW_BARRIER();
        MMAC(0, 0, bf0);
        RAW_BARRIER();

        // P1: read bf1; stage A-u0[j+2] + B-u0[j+2]
        if (buf == 0) LOADB(0, 1, bf1); else LOADB(1, 1, bf1);
        if (s2) {
            if (buf == 0) { STAGE_A(0, 0, ko2); STAGE_B(0, 0, ko2); }
            else          { STAGE_A(1, 0, ko2); STAGE_B(1, 0, ko2); }
        }
        RAW_BARRIER();
        MMAC(0, 1, bf1);
        RAW_BARRIER();

        // P2: read af(m1); stage B-u1[j+2]
        if (buf == 0) LOADA(0, 1); else LOADA(1, 1);
        if (s2) { if (buf == 0) STAGE_B(0, 32, ko2); else STAGE_B(1, 32, ko2); }
        RAW_BARRIER();
        MMAC(1, 0, bf0);
        RAW_BARRIER();

        // P3: stage A-u1[j+2]; counted wait confirms tile j+1
        if (s2) { if (buf == 0) STAGE_A(0, 64, ko2); else STAGE_A(1, 64, ko2); }
        if (j < NTt - 2) asm volatile("s_waitcnt vmcnt(8)" ::: "memory");
        else             asm volatile("s_waitcnt vmcnt(0)" ::: "memory");
        RAW_BARRIER();
        MMAC(1, 1, bf1);
        RAW_BARRIER();
    }

    // --- epilogue: bf16 partial store (C row = quad*4+reg, col = l16)
    unsigned short* P = z ? P1 : P0;
    #pragma unroll
    for (int mfg = 0; mfg < 8; mfg++) {
        const int row0 = mBase + wm * 128 + mfg * 16 + quad * 4;
        #pragma unroll
        for (int nfg = 0; nfg < 4; nfg++) {
            const int col = nBase + wn * 64 + nfg * 16 + l16;
            if (col < CDIM) {
                #pragma unroll
                for (int rg = 0; rg < 4; rg++)
                    P[(size_t)(row0 + rg) * CDIM + col] = f2bf(acc[mfg][nfg][rg]);
            }
        }
    }
}

// ---- bias + LOO-logsumexp; wave-per-row, no LDS, no syncthreads ----
// grid 2048 x 256: 4 waves/block, 1 row/wave; lane covers 16 cols.
__global__ __launch_bounds__(256) void lse_kernel(
    float* __restrict__ out,
    const unsigned short* P0, const unsigned short* P1,
    const float* __restrict__ bias, int split)
{
    const int wave = threadIdx.x >> 6;
    const int lane = threadIdx.x & 63;
    const int row  = blockIdx.x * 4 + wave;
    const int cb   = lane * 16;                 // 64 lanes x 16 = 1024 >= 1000

    float4 v[4], e[4];
    #pragma unroll
    for (int q = 0; q < 4; q++) {
        const int c0 = cb + q * 4;              // quad-aligned; 1000 % 4 == 0
        if (c0 < CDIM) {
            float4 vv;
            if (split) {
                ushort4 p0 = *(const ushort4*)(P0 + (size_t)row * CDIM + c0);
                ushort4 p1 = *(const ushort4*)(P1 + (size_t)row * CDIM + c0);
                vv.x = bf2f(p0.x) + bf2f(p1.x);
                vv.y = bf2f(p0.y) + bf2f(p1.y);
                vv.z = bf2f(p0.z) + bf2f(p1.z);
                vv.w = bf2f(p0.w) + bf2f(p1.w);
            } else {
                vv = *(const float4*)(out + (size_t)row * CDIM + c0);
            }
            float4 bb = *(const float4*)(bias + c0);
            vv.x += bb.x; vv.y += bb.y; vv.z += bb.z; vv.w += bb.w;
            v[q] = vv;
        } else {
            v[q] = make_float4(-INFINITY, -INFINITY, -INFINITY, -INFINITY);
        }
    }

    float m = -INFINITY;
    #pragma unroll
    for (int q = 0; q < 4; q++)
        m = fmaxf(m, fmaxf(fmaxf(v[q].x, v[q].y), fmaxf(v[q].z, v[q].w)));
    #pragma unroll
    for (int off = 1; off < 64; off <<= 1)
        m = fmaxf(m, __shfl_xor(m, off, 64));
    const float M = m;

    float s = 0.f;
    #pragma unroll
    for (int q = 0; q < 4; q++) {
        const int c0 = cb + q * 4;
        if (c0 < CDIM) {
            e[q].x = expf(v[q].x - M); e[q].y = expf(v[q].y - M);
            e[q].z = expf(v[q].z - M); e[q].w = expf(v[q].w - M);
            s += e[q].x + e[q].y + e[q].z + e[q].w;
        } else {
            e[q] = make_float4(0.f, 0.f, 0.f, 0.f);
        }
    }
    #pragma unroll
    for (int off = 1; off < 64; off <<= 1)
        s += __shfl_xor(s, off, 64);

    const float S    = s;
    const float lse  = M + logf(S);
    const float invS = 1.0f / S;

    #pragma unroll
    for (int q = 0; q < 4; q++) {
        const int c0 = cb + q * 4;
        if (c0 < CDIM) {
            float4 o;
            o.x = (v[q].x - lse) - log1pf(-e[q].x * invS);
            o.y = (v[q].y - lse) - log1pf(-e[q].y * invS);
            o.z = (v[q].z - lse) - log1pf(-e[q].z * invS);
            o.w = (v[q].w - lse) - log1pf(-e[q].w * invS);
            *(float4*)(out + (size_t)row * CDIM + c0) = o;
        }
    }
}

extern "C" void kernel_launch(void* const* d_in, const int* in_sizes, int n_in,
                              void* d_out, int out_size, void* d_ws, size_t ws_size,
                              hipStream_t stream) {
    const float* x = (const float*)d_in[0];   // [8192, 2048]
    const float* W = (const float*)d_in[1];   // [2048, 1000]
    const float* b = (const float*)d_in[2];   // [1000]
    float* out = (float*)d_out;               // [8192, 1000]

    unsigned short* xb = (unsigned short*)d_ws;
    unsigned short* Bt = (unsigned short*)((char*)d_ws + WS_BT_OFFSET);
    unsigned short* P0 = (unsigned short*)((char*)d_ws + WS_P0_OFFSET);
    unsigned short* P1 = (unsigned short*)((char*)d_ws + WS_P1_OFFSET);
    const bool splitk = ws_size >= WS_NEED;   // constant across calls

    // 1) fused x->bf16 + W->Bt (2048 + 2048 blocks, grid-stride x part)
    cvt_kernel<<<4096, 256, 0, stream>>>(x, xb, W, Bt);

    // 2) GEMM + 3) LOO-LSE
    if (splitk) {
        gemm8_kernel<<<256, 512, 0, stream>>>(xb, Bt, P0, P1);
        lse_kernel<<<2048, 256, 0, stream>>>(out, P0, P1, b, 1);
    } else {
        gemm_single_kernel<<<512, 256, 0, stream>>>(xb, Bt, out);
        lse_kernel<<<2048, 256, 0, stream>>>(out, nullptr, nullptr, b, 0);
    }
}

// Round 3
// 175.597 us; speedup vs baseline: 1.0518x; 1.0518x over previous
//
#include <hip/hip_runtime.h>
#include <hip/hip_bf16.h>
#include <math.h>

#define BDIM 8192
#define DDIM 2048
#define CDIM 1000
#define NPAD 1024
#define BK   64

// ws layout (bytes):
//   xb bf16 [8192*2048] = 33554432 @ 0
//   Bt bf16 [1024*2048] =  4194304 @ 33554432
//   P0 bf16 [8192*1000] = 16384000 @ 37748736   (split-K partial, k-half 0)
//   P1 bf16 [8192*1000] = 16384000 @ 54132736   (split-K partial, k-half 1)
// total = 70516736
#define WS_BT_OFFSET  33554432ULL
#define WS_P0_OFFSET  37748736ULL
#define WS_P1_OFFSET  54132736ULL
#define WS_NEED       70516736ULL

typedef __attribute__((ext_vector_type(8))) short short8;
typedef __attribute__((ext_vector_type(4))) float floatx4;

__device__ __forceinline__ unsigned short f2bf(float f) {
    union { float f; unsigned u; } a; a.f = f;
    unsigned u = a.u;
    u = (u + 0x7fff + ((u >> 16) & 1)) >> 16;   // RNE, finite inputs
    return (unsigned short)u;
}

__device__ __forceinline__ float bf2f(unsigned short h) {
    union { unsigned u; float f; } a; a.u = ((unsigned)h) << 16;
    return a.f;
}

__device__ __forceinline__ void async_copy16(const void* gp, void* lp) {
    __builtin_amdgcn_global_load_lds(
        (const __attribute__((address_space(1))) void*)gp,
        (__attribute__((address_space(3))) void*)lp,
        16, 0, 0);
}

// ---- kernel 1: fused x->bf16 (blocks 0..16383) and W->Bt transpose (blocks 16384..18431) ----
__global__ __launch_bounds__(256) void cvt_kernel(
    const float* __restrict__ x, unsigned short* __restrict__ xb,
    const float* __restrict__ W, unsigned short* __restrict__ Bt)
{
    const int blk = blockIdx.x;
    const int t   = threadIdx.x;
    if (blk < 16384) {
        int i = blk * 256 + t;
        float4 v = ((const float4*)x)[i];
        ushort4 o;
        o.x = f2bf(v.x); o.y = f2bf(v.y); o.z = f2bf(v.z); o.w = f2bf(v.w);
        ((ushort4*)xb)[i] = o;
    } else {
        __shared__ float tile[32][33];
        const int b2 = blk - 16384;          // 64 k-tiles x 32 n-tiles
        const int k0 = (b2 & 63) * 32;
        const int n0 = (b2 >> 6) * 32;
        const int tx = t & 31, ty = t >> 5;  // 32 x 8
        #pragma unroll
        for (int i = 0; i < 4; i++) {
            int k = k0 + ty + i * 8;
            int n = n0 + tx;
            tile[ty + i * 8][tx] = (n < CDIM) ? W[(size_t)k * CDIM + n] : 0.0f;
        }
        __syncthreads();
        #pragma unroll
        for (int i = 0; i < 4; i++) {
            int n = n0 + ty + i * 8;
            int k = k0 + tx;
            Bt[(size_t)n * DDIM + k] = f2bf(tile[tx][ty + i * 8]);
        }
    }
}

// ---- fallback GEMM body (R7 structure) for the small-ws path ----
template <bool BF16OUT>
__device__ __forceinline__ void gemm_body(
    const unsigned short* __restrict__ A,
    const unsigned short* __restrict__ Bt,
    void* __restrict__ Cv,
    int mBase, int nBase, int kBase, int kIters,
    unsigned short* As, unsigned short* Bs)
{
    const int t    = threadIdx.x;
    const int wave = t >> 6;
    const int lane = t & 63;
    const int wm   = wave & 1;
    const int wn   = wave >> 1;
    const int quad = lane >> 4;
    const int l16  = lane & 15;

    floatx4 acc[4][4] = {};

    const int rowA = t >> 3;
    const int csw  = ((t & 7) ^ (rowA & 7)) * 16;
    const char* Ag = (const char*)A  + ((size_t)(mBase + rowA) * DDIM + kBase) * 2 + csw;
    const char* Bg = (const char*)Bt + ((size_t)(nBase + rowA) * DDIM + kBase) * 2 + csw;
    char* AsDst = (char*)As + t * 16;
    char* BsDst = (char*)Bs + t * 16;

    const int xorb0 = ((0 * 4 + quad) ^ (l16 & 7)) * 8;
    const int xorb1 = ((1 * 4 + quad) ^ (l16 & 7)) * 8;

    for (int kt = 0; kt < kIters * BK; kt += BK) {
        const char* a = Ag + kt * 2;
        const char* b = Bg + kt * 2;
        #pragma unroll
        for (int r = 0; r < 4; r++) {
            async_copy16(a + (size_t)r * 32 * DDIM * 2, AsDst + r * 4096);
            async_copy16(b + (size_t)r * 32 * DDIM * 2, BsDst + r * 4096);
        }
        __syncthreads();

        #pragma unroll
        for (int ks = 0; ks < 2; ks++) {
            const int xorb = ks ? xorb1 : xorb0;
            short8 af[4], bfr[4];
            #pragma unroll
            for (int mi = 0; mi < 4; mi++)
                af[mi] = *(const short8*)(As + (wm * 64 + mi * 16 + l16) * BK + xorb);
            #pragma unroll
            for (int ni = 0; ni < 4; ni++)
                bfr[ni] = *(const short8*)(Bs + (wn * 64 + ni * 16 + l16) * BK + xorb);
            #pragma unroll
            for (int mi = 0; mi < 4; mi++)
                #pragma unroll
                for (int ni = 0; ni < 4; ni++)
                    acc[mi][ni] = __builtin_amdgcn_mfma_f32_16x16x32_bf16(
                        af[mi], bfr[ni], acc[mi][ni], 0, 0, 0);
        }
        __syncthreads();
    }

    #pragma unroll
    for (int mi = 0; mi < 4; mi++) {
        int row0 = mBase + wm * 64 + mi * 16 + quad * 4;
        #pragma unroll
        for (int ni = 0; ni < 4; ni++) {
            int col = nBase + wn * 64 + ni * 16 + l16;
            if (col < CDIM) {
                #pragma unroll
                for (int rg = 0; rg < 4; rg++) {
                    if (BF16OUT)
                        ((unsigned short*)Cv)[(size_t)(row0 + rg) * CDIM + col] =
                            f2bf(acc[mi][ni][rg]);
                    else
                        ((float*)Cv)[(size_t)(row0 + rg) * CDIM + col] = acc[mi][ni][rg];
                }
            }
        }
    }
}

// ---- single-K fallback: grid 512, fp32 out ----
__global__ __launch_bounds__(256, 2) void gemm_single_kernel(
    const unsigned short* __restrict__ A,
    const unsigned short* __restrict__ Bt,
    float* __restrict__ C0)
{
    __shared__ unsigned short As[128 * BK];
    __shared__ unsigned short Bs[128 * BK];

    const int L   = blockIdx.x;          // 0..511
    const int xcd = L & 7;
    const int s   = L >> 3;              // 0..63
    const int m_t = xcd * 8 + (s >> 3);
    const int n_t = s & 7;

    gemm_body<false>(A, Bt, C0, m_t * 128, n_t * 128, 0, DDIM / BK, As, Bs);
}

// =====================================================================
// 4-region 256x256 split-K GEMM (R3).  One barrier per C-quadrant:
//   region q:  { stage 2 async loads ; 16 MFMA(q) ; ds_reads for q+1 ;
//                [vmcnt @q2 / lgkmcnt(0) @q3] ; s_barrier }
// Reads are pipelined one quadrant ahead so the other SIMD-wave's MFMA
// overlaps the LDS pipe; barriers drop from 8 to 4 per K-tile.
// Quadrant (MQ,NQ) read rows:  A-u0={0-63,128-191} (MQ=0),
//   A-u1={64-127,192-255} (MQ=1), B-u0={0-31,64-95,128-159,192-223}
//   (NQ=0), B-u1=complement (NQ=1).
// Hazard edges (overwrite >= 1 barrier after readers complete):
//   stage A-u0@q0(j) vs af0 reads@q3(j-1): lgkmcnt(0) before BAR(q3).
//   stage B-u0@q1 vs bf0 reads@q3(j-1): same barrier chain.
//   stage B-u1@q2 vs bf1 reads@q0: bf1 complete before BAR(q1) (MFMA
//   lgkm wait at q1), stage is after BAR(q1).
//   stage A-u1@q3 vs af1 reads@q1: complete before BAR(q2).
// vmcnt(6)@q2(j): outstanding = tile j+2's 6 issued units (+ tile j+1
// A-u1); FIFO => all of tile j+1 confirmed before BAR(q2), so q3's
// cross-buffer reads of tile j+1 are safe.
// =====================================================================

#define HBUF (256 * BK)   // ushorts per buffer half (32 KiB)

#define STAGE_A2(BASE, EXT, KO)                                               \
    do {                                                                      \
        _Pragma("unroll")                                                     \
        for (int h = 0; h < 2; h++) {                                         \
            const int row_ = rA0 + (EXT) + h * 128;                           \
            async_copy16(gA + (size_t)row_ * DDIM + (KO),                     \
                         (BASE) + row_ * BK + c8);                            \
        }                                                                     \
    } while (0)

#define STAGE_B2(BASE, EXT, KO)                                               \
    do {                                                                      \
        _Pragma("unroll")                                                     \
        for (int h = 0; h < 2; h++) {                                         \
            const int row_ = rB0 + (EXT) + h * 128;                           \
            async_copy16(gB + (size_t)row_ * DDIM + (KO),                     \
                         (BASE) + row_ * BK + c8);                            \
        }                                                                     \
    } while (0)

#define LOADA_(BASE, MQ)                                                      \
    do {                                                                      \
        _Pragma("unroll")                                                     \
        for (int mf = 0; mf < 4; mf++) {                                      \
            const int r_ = (arA + (MQ) * 64 + mf * 16) * BK;                  \
            af[mf][0] = *(const short8*)((BASE) + r_ + xorb0);                \
            af[mf][1] = *(const short8*)((BASE) + r_ + xorb1);                \
        }                                                                     \
    } while (0)

#define LOADB_(BASE, NQ, BF)                                                  \
    do {                                                                      \
        _Pragma("unroll")                                                     \
        for (int nf = 0; nf < 2; nf++) {                                      \
            const int r_ = (arB + (NQ) * 32 + nf * 16) * BK;                  \
            BF[nf][0] = *(const short8*)((BASE) + r_ + xorb0);                \
            BF[nf][1] = *(const short8*)((BASE) + r_ + xorb1);                \
        }                                                                     \
    } while (0)

#define MMAC(MQ, NQ, BF)                                                      \
    do {                                                                      \
        __builtin_amdgcn_s_setprio(1);                                        \
        _Pragma("unroll")                                                     \
        for (int mf = 0; mf < 4; mf++) {                                      \
            _Pragma("unroll")                                                 \
            for (int nf = 0; nf < 2; nf++) {                                  \
                floatx4 c_ = acc[(MQ) * 4 + mf][(NQ) * 2 + nf];               \
                c_ = __builtin_amdgcn_mfma_f32_16x16x32_bf16(                 \
                    af[mf][0], BF[nf][0], c_, 0, 0, 0);                       \
                c_ = __builtin_amdgcn_mfma_f32_16x16x32_bf16(                 \
                    af[mf][1], BF[nf][1], c_, 0, 0, 0);                       \
                acc[(MQ) * 4 + mf][(NQ) * 2 + nf] = c_;                       \
            }                                                                 \
        }                                                                     \
        __builtin_amdgcn_s_setprio(0);                                        \
    } while (0)

#define RAW_BARRIER() asm volatile("s_barrier" ::: "memory")
#define WAIT_VM(N)    asm volatile("s_waitcnt vmcnt(" #N ")" ::: "memory")
#define WAIT_LGKM0()  asm volatile("s_waitcnt lgkmcnt(0)" ::: "memory")

__global__ __launch_bounds__(512) void gemm8_kernel(
    const unsigned short* __restrict__ A,
    const unsigned short* __restrict__ Bt,
    unsigned short* __restrict__ P0, unsigned short* __restrict__ P1)
{
    __shared__ unsigned short As[2 * HBUF];
    __shared__ unsigned short Bs[2 * HBUF];

    const int t    = threadIdx.x;
    const int wave = t >> 6;
    const int lane = t & 63;
    const int wm   = wave >> 2;          // 0..1  (M half)
    const int wn   = wave & 3;           // 0..3  (N quarter)
    const int quad = lane >> 4;
    const int l16  = lane & 15;

    // XCD-swizzled block mapping: 256 blocks -> 8 XCDs x 32.
    const int L    = blockIdx.x;
    const int g    = (L & 7) * 32 + (L >> 3);   // bijective, nwg%8==0
    const int z    = g & 1;                     // K-split
    const int tid2 = g >> 1;                    // 0..127
    const int mBase = (tid2 >> 2) * 256;
    const int nBase = (tid2 & 3) * 256;
    const int kBase = z * (DDIM / 2);
    const int NTt   = (DDIM / 2) / BK;          // 16 K-tiles

    // --- staging precompute
    const int c8  = (t & 7) << 3;               // dst chunk col (ushorts)
    const int q0  = t >> 3;                     // 0..63
    const int csw = (((t & 7) ^ (q0 & 7)) << 3);// pre-swizzled src chunk
    const int rA0 = q0;                         // A-u0 rows: q0, q0+128
    const int rB0 = q0 + (q0 & 32);             // B-u0 rows: rb, rb+128
    const unsigned short* gA = A  + (size_t)mBase * DDIM + kBase + csw;
    const unsigned short* gB = Bt + (size_t)nBase * DDIM + kBase + csw;

    // --- fragment-read precompute
    const int xorb0 = ((0 * 4 + quad) ^ (l16 & 7)) << 3;
    const int xorb1 = ((1 * 4 + quad) ^ (l16 & 7)) << 3;
    const int arA = wm * 128 + l16;
    const int arB = wn * 64 + l16;

    floatx4 acc[8][4] = {};
    short8 af[4][2], bf0[2][2], bf1[2][2];

    // --- prologue: stage tile0 (half 0) + tile1 (half 1), confirm tile0,
    //     pre-read tile0's af(m0)+bf(n0), then one extra barrier so q0's
    //     staging can't race the pre-reads.
    STAGE_A2(As, 0, 0);
    STAGE_A2(As, 64, 0);
    STAGE_B2(Bs, 0, 0);
    STAGE_B2(Bs, 32, 0);
    STAGE_A2(As + HBUF, 0, BK);
    STAGE_A2(As + HBUF, 64, BK);
    STAGE_B2(Bs + HBUF, 0, BK);
    STAGE_B2(Bs + HBUF, 32, BK);
    WAIT_VM(8);                 // tile0 landed (tile1's 8 still in flight)
    RAW_BARRIER();
    LOADA_(As, 0);
    LOADB_(Bs, 0, bf0);
    WAIT_LGKM0();
    RAW_BARRIER();

    for (int j = 0; j < NTt; j++) {
        const int bo = (j & 1) * HBUF;
        unsigned short* const cA = (unsigned short*)As + bo;
        unsigned short* const cB = (unsigned short*)Bs + bo;
        const unsigned short* const nA = (const unsigned short*)As + (bo ^ HBUF);
        const unsigned short* const nB = (const unsigned short*)Bs + (bo ^ HBUF);
        const int  ko2 = (j + 2) * BK;
        const bool s2  = (j + 2 < NTt);

        // q0: stage A-u0[j+2]; MFMA(0,0); read bf1 (tile j)
        if (s2) STAGE_A2(cA, 0, ko2);
        MMAC(0, 0, bf0);
        LOADB_(cB, 1, bf1);
        RAW_BARRIER();

        // q1: stage B-u0[j+2]; MFMA(0,1); read af(m1) (tile j)
        if (s2) STAGE_B2(cB, 0, ko2);
        MMAC(0, 1, bf1);
        LOADA_(cA, 1);
        RAW_BARRIER();

        // q2: stage B-u1[j+2]; MFMA(1,0); counted vmcnt confirms tile j+1
        if (s2) STAGE_B2(cB, 32, ko2);
        MMAC(1, 0, bf0);
        if (j < NTt - 2) WAIT_VM(6);
        else             WAIT_VM(0);
        RAW_BARRIER();

        // q3: stage A-u1[j+2]; MFMA(1,1); read next tile's af(m0)+bf(n0)
        if (s2) STAGE_A2(cA, 64, ko2);
        MMAC(1, 1, bf1);
        if (j + 1 < NTt) { LOADA_(nA, 0); LOADB_(nB, 0, bf0); }
        WAIT_LGKM0();
        RAW_BARRIER();
    }

    // --- epilogue: bf16 partial store (C row = quad*4+reg, col = l16)
    unsigned short* P = z ? P1 : P0;
    #pragma unroll
    for (int mfg = 0; mfg < 8; mfg++) {
        const int row0 = mBase + wm * 128 + mfg * 16 + quad * 4;
        #pragma unroll
        for (int nfg = 0; nfg < 4; nfg++) {
            const int col = nBase + wn * 64 + nfg * 16 + l16;
            if (col < CDIM) {
                #pragma unroll
                for (int rg = 0; rg < 4; rg++)
                    P[(size_t)(row0 + rg) * CDIM + col] = f2bf(acc[mfg][nfg][rg]);
            }
        }
    }
}

// ---- bias + LOO-logsumexp; split: sum two bf16 partials -> fp32 out ----
__global__ __launch_bounds__(256) void lse_kernel(
    float* __restrict__ out,
    const unsigned short* P0, const unsigned short* P1,
    const float* __restrict__ bias, int split)
{
    const int row = blockIdx.x;
    const int t   = threadIdx.x;
    __shared__ float red[8];

    const bool valid = t < (CDIM / 4);   // 250 threads x 4 cols
    const int c0 = t * 4;

    float4 v = make_float4(-INFINITY, -INFINITY, -INFINITY, -INFINITY);
    float4 e = make_float4(0.f, 0.f, 0.f, 0.f);
    if (valid) {
        if (split) {
            ushort4 p0 = *(const ushort4*)(P0 + (size_t)row * CDIM + c0);
            ushort4 p1 = *(const ushort4*)(P1 + (size_t)row * CDIM + c0);
            v.x = bf2f(p0.x) + bf2f(p1.x);
            v.y = bf2f(p0.y) + bf2f(p1.y);
            v.z = bf2f(p0.z) + bf2f(p1.z);
            v.w = bf2f(p0.w) + bf2f(p1.w);
        } else {
            v = *(const float4*)(out + (size_t)row * CDIM + c0);
        }
        float4 bb = *(const float4*)(bias + c0);
        v.x += bb.x; v.y += bb.y; v.z += bb.z; v.w += bb.w;
    }

    float m = fmaxf(fmaxf(v.x, v.y), fmaxf(v.z, v.w));
    #pragma unroll
    for (int off = 32; off > 0; off >>= 1)
        m = fmaxf(m, __shfl_down(m, off, 64));
    const int wave = t >> 6;
    if ((t & 63) == 0) red[wave] = m;
    __syncthreads();
    if (t == 0) red[4] = fmaxf(fmaxf(red[0], red[1]), fmaxf(red[2], red[3]));
    __syncthreads();
    const float M = red[4];

    float s = 0.f;
    if (valid) {
        e.x = expf(v.x - M); e.y = expf(v.y - M);
        e.z = expf(v.z - M); e.w = expf(v.w - M);
        s = e.x + e.y + e.z + e.w;
    }
    #pragma unroll
    for (int off = 32; off > 0; off >>= 1)
        s += __shfl_down(s, off, 64);
    if ((t & 63) == 0) red[wave] = s;
    __syncthreads();
    if (t == 0) red[4] = red[0] + red[1] + red[2] + red[3];
    __syncthreads();
    const float S    = red[4];
    const float lse  = M + logf(S);
    const float invS = 1.0f / S;

    if (valid) {
        float4 o;
        o.x = (v.x - lse) - log1pf(-e.x * invS);
        o.y = (v.y - lse) - log1pf(-e.y * invS);
        o.z = (v.z - lse) - log1pf(-e.z * invS);
        o.w = (v.w - lse) - log1pf(-e.w * invS);
        *(float4*)(out + (size_t)row * CDIM + c0) = o;
    }
}

extern "C" void kernel_launch(void* const* d_in, const int* in_sizes, int n_in,
                              void* d_out, int out_size, void* d_ws, size_t ws_size,
                              hipStream_t stream) {
    const float* x = (const float*)d_in[0];   // [8192, 2048]
    const float* W = (const float*)d_in[1];   // [2048, 1000]
    const float* b = (const float*)d_in[2];   // [1000]
    float* out = (float*)d_out;               // [8192, 1000]

    unsigned short* xb = (unsigned short*)d_ws;
    unsigned short* Bt = (unsigned short*)((char*)d_ws + WS_BT_OFFSET);
    unsigned short* P0 = (unsigned short*)((char*)d_ws + WS_P0_OFFSET);
    unsigned short* P1 = (unsigned short*)((char*)d_ws + WS_P1_OFFSET);
    const bool splitk = ws_size >= WS_NEED;   // constant across calls

    // 1) fused x->bf16 + W->Bt (16384 + 2048 blocks)
    cvt_kernel<<<18432, 256, 0, stream>>>(x, xb, W, Bt);

    // 2) GEMM + 3) LOO-LSE
    if (splitk) {
        gemm8_kernel<<<256, 512, 0, stream>>>(xb, Bt, P0, P1);
        lse_kernel<<<BDIM, 256, 0, stream>>>(out, P0, P1, b, 1);
    } else {
        gemm_single_kernel<<<512, 256, 0, stream>>>(xb, Bt, out);
        lse_kernel<<<BDIM, 256, 0, stream>>>(out, nullptr, nullptr, b, 0);
    }
}